// Round 4
// baseline (501.185 us; speedup 1.0000x reference)
//
#include <hip/hip_runtime.h>
#include <math.h>

#define NB    16
#define NPIX  4096    // 64*64
#define NPOOL 1024    // 32*32
#define CIN   512
#define CD    64      // C/8
#define CG    256     // C/2

typedef unsigned short u16;
typedef unsigned int   u32;
typedef __attribute__((ext_vector_type(8)))  u16    u16x8;
typedef __attribute__((ext_vector_type(8)))  __bf16 bf16x8;
typedef __attribute__((ext_vector_type(16))) float  f32x16;

__device__ __forceinline__ u16 f2bf(float x) {
    u32 u = __builtin_bit_cast(u32, x);
    u += 0x7fffu + ((u >> 16) & 1u);          // round-to-nearest-even
    return (u16)(u >> 16);
}
__device__ __forceinline__ float bf2f(u16 h) {
    u32 u = ((u32)h) << 16;
    return __builtin_bit_cast(float, u);
}
__device__ __forceinline__ f32x16 mfma32(u16x8 a, u16x8 b, f32x16 c) {
    return __builtin_amdgcn_mfma_f32_32x32x16_bf16(
        __builtin_bit_cast(bf16x8, a), __builtin_bit_cast(bf16x8, b), c, 0, 0, 0);
}

// ---------------------------------------------------------------------------
// Kernel 0: prep — transpose weights to bf16 [n][k] layout + concat bias.
// ---------------------------------------------------------------------------
__global__ __launch_bounds__(256) void prep_kernel(
    const float* __restrict__ wt, const float* __restrict__ wp,
    const float* __restrict__ wg, const float* __restrict__ wo,
    const float* __restrict__ bt, const float* __restrict__ bp,
    const float* __restrict__ bg,
    u16* __restrict__ WT, u16* __restrict__ WOT, float* __restrict__ biasP)
{
    const int bx = blockIdx.x;
    const int t  = threadIdx.x;

    if (bx == 320) {
        for (int i = t; i < 384; i += 256)
            biasP[i] = (i < 64) ? bt[i] : (i < 128) ? bp[i - 64] : bg[i - 128];
        return;
    }

    const float* src; u16* dst; int N, K, kt, nt;
    if (bx < 32)       { src = wt; dst = WT;             N = 64;  K = 512; kt = bx >> 1;        nt = bx & 1; }
    else if (bx < 64)  { src = wp; dst = WT + 64 * 512;  N = 64;  K = 512; kt = (bx - 32) >> 1; nt = (bx - 32) & 1; }
    else if (bx < 192) { src = wg; dst = WT + 128 * 512; N = 256; K = 512; kt = (bx - 64) >> 3; nt = (bx - 64) & 7; }
    else               { src = wo; dst = WOT;            N = 512; K = 256; kt = (bx - 192) >> 4; nt = (bx - 192) & 15; }

    __shared__ float tile[32][33];
    {
        int r  = t >> 3;            // 0..31 source row (k)
        int c4 = (t & 7) * 4;       // 0..28 source col (n)
        float4 v = *(const float4*)(src + (size_t)(kt * 32 + r) * N + nt * 32 + c4);
        tile[r][c4]     = v.x;
        tile[r][c4 + 1] = v.y;
        tile[r][c4 + 2] = v.z;
        tile[r][c4 + 3] = v.w;
    }
    __syncthreads();
    {
        int n  = t >> 3;            // 0..31 dst row (n)
        int k4 = (t & 7) * 4;       // 0..28 dst col (k)
        ushort4 wv;
        wv.x = f2bf(tile[k4][n]);
        wv.y = f2bf(tile[k4 + 1][n]);
        wv.z = f2bf(tile[k4 + 2][n]);
        wv.w = f2bf(tile[k4 + 3][n]);
        *(ushort4*)(dst + (size_t)(nt * 32 + n) * K + kt * 32 + k4) = wv;
    }
}

// ---------------------------------------------------------------------------
// Kernel 1: proj GEMM (MFMA).  C[65536 x 384] = x(bf16-cast) @ WT^T.
// 128x128 tile, 4 waves each 64x64 (2x2 of 32x32x16 MFMA), BK=32.
// XCD swizzle: 1536 = 8 x 192 (bijective).
// ---------------------------------------------------------------------------
#define AST 40   // LDS row stride in bf16 (32 + 8 pad, 80B = 16B-aligned)
__global__ __launch_bounds__(256) void proj_gemm_kernel(
    const float* __restrict__ x, const u16* __restrict__ WT,
    const float* __restrict__ biasP,
    u16* __restrict__ theta, u16* __restrict__ phiF, u16* __restrict__ gF)
{
    __shared__ u16 As[128 * AST];   // 10 KB
    __shared__ u16 Bs[128 * AST];   // 10 KB

    const int t  = threadIdx.x;
    const int w  = t >> 6, l = t & 63, lr = l & 31, lh = l >> 5;
    const int sb = (blockIdx.x & 7) * 192 + (blockIdx.x >> 3);   // 1536 = 8*192
    const int mt = sb / 3, nt = sb % 3;
    const int m0 = mt * 128, n0 = nt * 128;
    const int mw = (w & 1) * 64, nw = (w >> 1) * 64;

    const int srow = t >> 1;             // staging row 0..127
    const int sks  = (t & 1) * 16;       // staging k offset

    f32x16 acc[2][2] = {};

    for (int k0 = 0; k0 < 512; k0 += 32) {
        // --- stage A: x fp32 -> bf16 ---
        {
            const float4* ap = (const float4*)(x + (size_t)(m0 + srow) * 512 + k0 + sks);
            float4 v0 = ap[0], v1 = ap[1], v2 = ap[2], v3 = ap[3];
            u16x8 a0, a1;
            a0[0] = f2bf(v0.x); a0[1] = f2bf(v0.y); a0[2] = f2bf(v0.z); a0[3] = f2bf(v0.w);
            a0[4] = f2bf(v1.x); a0[5] = f2bf(v1.y); a0[6] = f2bf(v1.z); a0[7] = f2bf(v1.w);
            a1[0] = f2bf(v2.x); a1[1] = f2bf(v2.y); a1[2] = f2bf(v2.z); a1[3] = f2bf(v2.w);
            a1[4] = f2bf(v3.x); a1[5] = f2bf(v3.y); a1[6] = f2bf(v3.z); a1[7] = f2bf(v3.w);
            *(u16x8*)&As[srow * AST + sks]     = a0;
            *(u16x8*)&As[srow * AST + sks + 8] = a1;
        }
        // --- stage B: WT bf16 ---
        {
            const u16x8* bp = (const u16x8*)(WT + (size_t)(n0 + srow) * 512 + k0 + sks);
            *(u16x8*)&Bs[srow * AST + sks]     = bp[0];
            *(u16x8*)&Bs[srow * AST + sks + 8] = bp[1];
        }
        __syncthreads();
#pragma unroll
        for (int ki = 0; ki < 2; ++ki) {
            u16x8 af0 = *(const u16x8*)&As[(mw + lr)      * AST + ki * 16 + lh * 8];
            u16x8 af1 = *(const u16x8*)&As[(mw + 32 + lr) * AST + ki * 16 + lh * 8];
            u16x8 bf0 = *(const u16x8*)&Bs[(nw + lr)      * AST + ki * 16 + lh * 8];
            u16x8 bf1 = *(const u16x8*)&Bs[(nw + 32 + lr) * AST + ki * 16 + lh * 8];
            acc[0][0] = mfma32(af0, bf0, acc[0][0]);
            acc[0][1] = mfma32(af0, bf1, acc[0][1]);
            acc[1][0] = mfma32(af1, bf0, acc[1][0]);
            acc[1][1] = mfma32(af1, bf1, acc[1][1]);
        }
        __syncthreads();
    }

    // --- epilogue: bias + column split (segment is wave-uniform per ni) ---
#pragma unroll
    for (int mi = 0; mi < 2; ++mi) {
#pragma unroll
        for (int ni = 0; ni < 2; ++ni) {
            const int nb = n0 + nw + ni * 32;       // segment base (uniform)
            const int n  = nb + lr;
            const float bv = biasP[n];
            u16* dst; int ld, col;
            if (nb < 64)        { dst = theta; ld = 64;  col = n; }
            else if (nb < 128)  { dst = phiF;  ld = 64;  col = n - 64; }
            else                { dst = gF;    ld = 256; col = n - 128; }
#pragma unroll
            for (int r = 0; r < 16; ++r) {
                int row = m0 + mw + mi * 32 + (r & 3) + 8 * (r >> 2) + 4 * lh;
                dst[(size_t)row * ld + col] = f2bf(acc[mi][ni][r] + bv);
            }
        }
    }
}

// ---------------------------------------------------------------------------
// Kernel 2: 2x2 max-pool of phiF/gF + transpose of g.
// ---------------------------------------------------------------------------
__global__ __launch_bounds__(256) void pool_kernel(
    const u16* __restrict__ phiF, const u16* __restrict__ gF,
    u16* __restrict__ phi, u16* __restrict__ gt)
{
    const int t  = threadIdx.x;
    const int b  = blockIdx.x >> 5;
    const int ph = blockIdx.x & 31;

    // --- phi: thread = (pw = t>>3, d-octet = t&7) ---
    {
        const int pw = t >> 3, dq = (t & 7) * 8;
        const u16* base = phiF + ((size_t)(b * NPIX + 2 * ph * 64 + 2 * pw)) * 64 + dq;
        u16x8 v00 = *(const u16x8*)(base);
        u16x8 v01 = *(const u16x8*)(base + 64);
        u16x8 v10 = *(const u16x8*)(base + 64 * 64);
        u16x8 v11 = *(const u16x8*)(base + 64 * 64 + 64);
        u16x8 m;
#pragma unroll
        for (int j = 0; j < 8; ++j) {
            float mf = fmaxf(fmaxf(bf2f(v00[j]), bf2f(v01[j])),
                             fmaxf(bf2f(v10[j]), bf2f(v11[j])));
            m[j] = f2bf(mf);
        }
        *(u16x8*)(phi + ((size_t)(b * NPOOL + ph * 32 + pw)) * 64 + dq) = m;
    }
    // --- gt: thread = channel d, loops 32 pool cols ---
    {
        const u16* gb = gF + ((size_t)(b * NPIX + 2 * ph * 64)) * 256 + t;
        u16 buf[32];
#pragma unroll
        for (int kp = 0; kp < 32; ++kp) {
            float m = fmaxf(
                fmaxf(bf2f(gb[(size_t)(2 * kp) * 256]),      bf2f(gb[(size_t)(2 * kp + 1) * 256])),
                fmaxf(bf2f(gb[(size_t)(64 + 2 * kp) * 256]), bf2f(gb[(size_t)(64 + 2 * kp + 1) * 256])));
            buf[kp] = f2bf(m);
        }
        u16* go = gt + ((size_t)(b * CG + t)) * NPOOL + ph * 32;
#pragma unroll
        for (int j = 0; j < 4; ++j)
            *(u16x8*)(go + j * 8) = *(const u16x8*)&buf[j * 8];
    }
}

// ---------------------------------------------------------------------------
// Kernel 3: MFMA attention — 64 q-rows per block, 1024 threads / 16 waves.
// 132 KB LDS -> 1 block/CU, but 16 waves = 4 waves/SIMD (was 2): the kernel
// is latency-bound (all pipes <30% busy), so doubling per-SIMD concurrency
// is the direct fix.  Same total LDS/L2 traffic as the 512-thread version.
// Phase 1: wave w computes S cols k in [w*64, w*64+64) for both q-tiles.
// Phase 3: wave w handles q-tile (w&1), output cols [(w>>1)*32, +32).
// XCD swizzle: 1024 = 8 x 128 (bijective); 2 batches per XCD stay L2-hot.
// ---------------------------------------------------------------------------
#define SLD 1032
__global__ __launch_bounds__(1024) void attn_mfma_kernel(
    const u16* __restrict__ theta, const u16* __restrict__ phi,
    const u16* __restrict__ gt, u16* __restrict__ attn_g)
{
    __shared__ u16   S[64 * SLD];         // 132 KB
    __shared__ float rinv[64];

    const int t  = threadIdx.x;
    const int w  = t >> 6;                // 0..15
    const int l  = t & 63;
    const int lr = l & 31;
    const int lh = l >> 5;
    const int sb = (blockIdx.x & 7) * 128 + (blockIdx.x >> 3);   // 1024 = 8*128
    const int b  = sb >> 6;
    const int q0 = (sb & 63) * 64;

    // ---- Phase 1: S = theta @ phi^T  (wave w: k in [w*64, w*64+64), both q-tiles) ----
    const u16* thb0 = theta + ((size_t)(b * NPIX + q0 + lr)) * CD + lh * 8;
    const u16* thb1 = thb0 + (size_t)32 * CD;
    u16x8 af0[4], af1[4];
#pragma unroll
    for (int ki = 0; ki < 4; ++ki) {
        af0[ki] = *(const u16x8*)(thb0 + ki * 16);
        af1[ki] = *(const u16x8*)(thb1 + ki * 16);
    }

    const u16* phb = phi + (size_t)b * NPOOL * CD;
#pragma unroll
    for (int nt = 0; nt < 2; ++nt) {
        int k0 = w * 64 + nt * 32;
        const u16* pb = phb + (size_t)(k0 + lr) * CD + lh * 8;
        u16x8 pf0 = *(const u16x8*)(pb);
        u16x8 pf1 = *(const u16x8*)(pb + 16);
        u16x8 pf2 = *(const u16x8*)(pb + 32);
        u16x8 pf3 = *(const u16x8*)(pb + 48);
        f32x16 acc0 = {}, acc1 = {};
        acc0 = mfma32(af0[0], pf0, acc0);  acc1 = mfma32(af1[0], pf0, acc1);
        acc0 = mfma32(af0[1], pf1, acc0);  acc1 = mfma32(af1[1], pf1, acc1);
        acc0 = mfma32(af0[2], pf2, acc0);  acc1 = mfma32(af1[2], pf2, acc1);
        acc0 = mfma32(af0[3], pf3, acc0);  acc1 = mfma32(af1[3], pf3, acc1);
#pragma unroll
        for (int r = 0; r < 16; ++r) {
            int row = (r & 3) + 8 * (r >> 2) + 4 * lh;
            S[row * SLD + k0 + lr]        = f2bf(acc0[r]);
            S[(32 + row) * SLD + k0 + lr] = f2bf(acc1[r]);
        }
    }
    __syncthreads();

    // ---- Phase 2: rowwise softmax (16 threads per row, 64 rows) ----
    {
        const int row = t >> 4, cg = t & 15;
        u16* srow = S + row * SLD;
        float mx = -1e30f;
#pragma unroll
        for (int i = 0; i < 8; ++i) {
            u16x8 v = *(const u16x8*)(srow + cg * 8 + 128 * i);
#pragma unroll
            for (int j = 0; j < 8; ++j) mx = fmaxf(mx, bf2f(v[j]));
        }
        mx = fmaxf(mx, __shfl_xor(mx, 1));
        mx = fmaxf(mx, __shfl_xor(mx, 2));
        mx = fmaxf(mx, __shfl_xor(mx, 4));
        mx = fmaxf(mx, __shfl_xor(mx, 8));
        float sum = 0.f;
#pragma unroll
        for (int i = 0; i < 8; ++i) {
            u16* p = srow + cg * 8 + 128 * i;
            u16x8 v = *(const u16x8*)p;
            u16x8 e;
#pragma unroll
            for (int j = 0; j < 8; ++j) {
                float ev = __expf(bf2f(v[j]) - mx);
                sum += ev;
                e[j] = f2bf(ev);
            }
            *(u16x8*)p = e;
        }
        sum += __shfl_xor(sum, 1);
        sum += __shfl_xor(sum, 2);
        sum += __shfl_xor(sum, 4);
        sum += __shfl_xor(sum, 8);
        if (cg == 0) rinv[row] = 1.0f / sum;
    }
    __syncthreads();

    // ---- Phase 3: O = P @ g  (wave w: q-tile qt = w&1, cols [(w>>1)*32, +32)) ----
    const int qt = w & 1, cg3 = w >> 1;
    const u16* gp  = gt + ((size_t)(b * CG + cg3 * 32 + lr)) * NPOOL + lh * 8;
    const u16* ar  = S + (qt * 32 + lr) * SLD + lh * 8;
    f32x16 oa = {}, ob2 = {};           // two independent chains over split K
#pragma unroll 8
    for (int k0 = 0; k0 < NPOOL; k0 += 32) {
        u16x8 a0 = *(const u16x8*)(ar + k0);
        u16x8 a1 = *(const u16x8*)(ar + k0 + 16);
        u16x8 b0 = *(const u16x8*)(gp + k0);
        u16x8 b1 = *(const u16x8*)(gp + k0 + 16);
        __builtin_amdgcn_s_setprio(1);
        oa  = mfma32(a0, b0, oa);
        ob2 = mfma32(a1, b1, ob2);
        __builtin_amdgcn_s_setprio(0);
    }

    u16* obp = attn_g + ((size_t)(b * NPIX + q0 + qt * 32)) * CG;
#pragma unroll
    for (int r = 0; r < 16; ++r) {
        int qrow = (r & 3) + 8 * (r >> 2) + 4 * lh;
        float inv = rinv[qt * 32 + qrow];
        obp[(size_t)qrow * CG + cg3 * 32 + lr] = f2bf((oa[r] + ob2[r]) * inv);
    }
}

// ---------------------------------------------------------------------------
// Kernel 4: out GEMM (MFMA).  out = x + sigma*(attn_g @ wo + bo).
// XCD swizzle: 2048 blocks = 8 x 256.
// ---------------------------------------------------------------------------
__global__ __launch_bounds__(256) void out_gemm_kernel(
    const u16* __restrict__ attn_gB, const u16* __restrict__ WOT,
    const float* __restrict__ x, const float* __restrict__ bo,
    const float* __restrict__ sigma, float* __restrict__ out)
{
    __shared__ u16 As[128 * AST];
    __shared__ u16 Bs[128 * AST];

    const int t  = threadIdx.x;
    const int w  = t >> 6, l = t & 63, lr = l & 31, lh = l >> 5;
    const int sb = (blockIdx.x & 7) * 256 + (blockIdx.x >> 3);   // 2048 = 8*256
    const int mt = sb >> 2, nt = sb & 3;
    const int m0 = mt * 128, n0 = nt * 128;
    const int mw = (w & 1) * 64, nw = (w >> 1) * 64;

    const int srow = t >> 1;
    const int sks  = (t & 1) * 16;

    f32x16 acc[2][2] = {};

    for (int k0 = 0; k0 < 256; k0 += 32) {
        {
            const u16x8* ap = (const u16x8*)(attn_gB + (size_t)(m0 + srow) * 256 + k0 + sks);
            *(u16x8*)&As[srow * AST + sks]     = ap[0];
            *(u16x8*)&As[srow * AST + sks + 8] = ap[1];
        }
        {
            const u16x8* bp = (const u16x8*)(WOT + (size_t)(n0 + srow) * 256 + k0 + sks);
            *(u16x8*)&Bs[srow * AST + sks]     = bp[0];
            *(u16x8*)&Bs[srow * AST + sks + 8] = bp[1];
        }
        __syncthreads();
#pragma unroll
        for (int ki = 0; ki < 2; ++ki) {
            u16x8 af0 = *(const u16x8*)&As[(mw + lr)      * AST + ki * 16 + lh * 8];
            u16x8 af1 = *(const u16x8*)&As[(mw + 32 + lr) * AST + ki * 16 + lh * 8];
            u16x8 bf0 = *(const u16x8*)&Bs[(nw + lr)      * AST + ki * 16 + lh * 8];
            u16x8 bf1 = *(const u16x8*)&Bs[(nw + 32 + lr) * AST + ki * 16 + lh * 8];
            acc[0][0] = mfma32(af0, bf0, acc[0][0]);
            acc[0][1] = mfma32(af0, bf1, acc[0][1]);
            acc[1][0] = mfma32(af1, bf0, acc[1][0]);
            acc[1][1] = mfma32(af1, bf1, acc[1][1]);
        }
        __syncthreads();
    }

    const float s = sigma[0];
#pragma unroll
    for (int mi = 0; mi < 2; ++mi) {
#pragma unroll
        for (int ni = 0; ni < 2; ++ni) {
            const int n  = n0 + nw + ni * 32 + lr;
            const float bv = bo[n];
#pragma unroll
            for (int r = 0; r < 16; ++r) {
                int row = m0 + mw + mi * 32 + (r & 3) + 8 * (r >> 2) + 4 * lh;
                size_t idx = (size_t)row * 512 + n;
                out[idx] = x[idx] + s * (acc[mi][ni][r] + bv);
            }
        }
    }
}

// ---------------------------------------------------------------------------
extern "C" void kernel_launch(void* const* d_in, const int* in_sizes, int n_in,
                              void* d_out, int out_size, void* d_ws, size_t ws_size,
                              hipStream_t stream)
{
    const float* x     = (const float*)d_in[0];
    const float* wt    = (const float*)d_in[1];
    const float* bt    = (const float*)d_in[2];
    const float* wp    = (const float*)d_in[3];
    const float* bp    = (const float*)d_in[4];
    const float* wg    = (const float*)d_in[5];
    const float* bg    = (const float*)d_in[6];
    const float* wo    = (const float*)d_in[7];
    const float* bo    = (const float*)d_in[8];
    const float* sigma = (const float*)d_in[9];
    float* out = (float*)d_out;

    char* ws = (char*)d_ws;
    u16*   theta   = (u16*)(ws);
    u16*   phi     = (u16*)(ws + ((size_t)8  << 20));
    u16*   phiF    = (u16*)(ws + ((size_t)10 << 20));
    u16*   gF      = (u16*)(ws + ((size_t)18 << 20));
    u16*   attn_gB = (u16*)(ws + ((size_t)10 << 20));
    u16*   gt      = (u16*)(ws + ((size_t)50 << 20));
    u16*   WT      = (u16*)(ws + ((size_t)58 << 20));
    u16*   WOT     = (u16*)(ws + ((size_t)58 << 20) + (384 << 10));
    float* biasP   = (float*)(ws + ((size_t)58 << 20) + (640 << 10));

    prep_kernel<<<321, 256, 0, stream>>>(wt, wp, wg, wo, bt, bp, bg, WT, WOT, biasP);
    proj_gemm_kernel<<<512 * 3, 256, 0, stream>>>(x, WT, biasP, theta, phiF, gF);
    pool_kernel<<<NB * 32, 256, 0, stream>>>(phiF, gF, phi, gt);
    attn_mfma_kernel<<<NB * NPIX / 64, 1024, 0, stream>>>(theta, phi, gt, attn_gB);
    out_gemm_kernel<<<512 * 4, 256, 0, stream>>>(attn_gB, WOT, x, bo, sigma, out);
}

// Round 5
// 417.480 us; speedup vs baseline: 1.2005x; 1.2005x over previous
//
#include <hip/hip_runtime.h>
#include <math.h>

#define NB    16
#define NPIX  4096    // 64*64
#define NPOOL 1024    // 32*32
#define CIN   512
#define CD    64      // C/8
#define CG    256     // C/2

typedef unsigned short u16;
typedef unsigned int   u32;
typedef __attribute__((ext_vector_type(8)))  u16    u16x8;
typedef __attribute__((ext_vector_type(8)))  __bf16 bf16x8;
typedef __attribute__((ext_vector_type(16))) float  f32x16;

__device__ __forceinline__ u16 f2bf(float x) {
    u32 u = __builtin_bit_cast(u32, x);
    u += 0x7fffu + ((u >> 16) & 1u);          // round-to-nearest-even
    return (u16)(u >> 16);
}
__device__ __forceinline__ float bf2f(u16 h) {
    u32 u = ((u32)h) << 16;
    return __builtin_bit_cast(float, u);
}
__device__ __forceinline__ f32x16 mfma32(u16x8 a, u16x8 b, f32x16 c) {
    return __builtin_amdgcn_mfma_f32_32x32x16_bf16(
        __builtin_bit_cast(bf16x8, a), __builtin_bit_cast(bf16x8, b), c, 0, 0, 0);
}

// ---------------------------------------------------------------------------
// Kernel 0: prep — transpose weights to bf16 [n][k] layout + concat bias.
// ---------------------------------------------------------------------------
__global__ __launch_bounds__(256) void prep_kernel(
    const float* __restrict__ wt, const float* __restrict__ wp,
    const float* __restrict__ wg, const float* __restrict__ wo,
    const float* __restrict__ bt, const float* __restrict__ bp,
    const float* __restrict__ bg,
    u16* __restrict__ WT, u16* __restrict__ WOT, float* __restrict__ biasP)
{
    const int bx = blockIdx.x;
    const int t  = threadIdx.x;

    if (bx == 320) {
        for (int i = t; i < 384; i += 256)
            biasP[i] = (i < 64) ? bt[i] : (i < 128) ? bp[i - 64] : bg[i - 128];
        return;
    }

    const float* src; u16* dst; int N, K, kt, nt;
    if (bx < 32)       { src = wt; dst = WT;             N = 64;  K = 512; kt = bx >> 1;        nt = bx & 1; }
    else if (bx < 64)  { src = wp; dst = WT + 64 * 512;  N = 64;  K = 512; kt = (bx - 32) >> 1; nt = (bx - 32) & 1; }
    else if (bx < 192) { src = wg; dst = WT + 128 * 512; N = 256; K = 512; kt = (bx - 64) >> 3; nt = (bx - 64) & 7; }
    else               { src = wo; dst = WOT;            N = 512; K = 256; kt = (bx - 192) >> 4; nt = (bx - 192) & 15; }

    __shared__ float tile[32][33];
    {
        int r  = t >> 3;            // 0..31 source row (k)
        int c4 = (t & 7) * 4;       // 0..28 source col (n)
        float4 v = *(const float4*)(src + (size_t)(kt * 32 + r) * N + nt * 32 + c4);
        tile[r][c4]     = v.x;
        tile[r][c4 + 1] = v.y;
        tile[r][c4 + 2] = v.z;
        tile[r][c4 + 3] = v.w;
    }
    __syncthreads();
    {
        int n  = t >> 3;            // 0..31 dst row (n)
        int k4 = (t & 7) * 4;       // 0..28 dst col (k)
        ushort4 wv;
        wv.x = f2bf(tile[k4][n]);
        wv.y = f2bf(tile[k4 + 1][n]);
        wv.z = f2bf(tile[k4 + 2][n]);
        wv.w = f2bf(tile[k4 + 3][n]);
        *(ushort4*)(dst + (size_t)(nt * 32 + n) * K + kt * 32 + k4) = wv;
    }
}

// ---------------------------------------------------------------------------
// Kernel 1: proj GEMM (MFMA).  C[65536 x 384] = x(bf16-cast) @ WT^T.
// 128x128 tile, 4 waves each 64x64 (2x2 of 32x32x16 MFMA), BK=32.
// XCD swizzle: 1536 = 8 x 192 (bijective).
// ---------------------------------------------------------------------------
#define AST 40   // LDS row stride in bf16 (32 + 8 pad, 80B = 16B-aligned)
__global__ __launch_bounds__(256) void proj_gemm_kernel(
    const float* __restrict__ x, const u16* __restrict__ WT,
    const float* __restrict__ biasP,
    u16* __restrict__ theta, u16* __restrict__ phiF, u16* __restrict__ gF)
{
    __shared__ u16 As[128 * AST];   // 10 KB
    __shared__ u16 Bs[128 * AST];   // 10 KB

    const int t  = threadIdx.x;
    const int w  = t >> 6, l = t & 63, lr = l & 31, lh = l >> 5;
    const int sb = (blockIdx.x & 7) * 192 + (blockIdx.x >> 3);   // 1536 = 8*192
    const int mt = sb / 3, nt = sb % 3;
    const int m0 = mt * 128, n0 = nt * 128;
    const int mw = (w & 1) * 64, nw = (w >> 1) * 64;

    const int srow = t >> 1;             // staging row 0..127
    const int sks  = (t & 1) * 16;       // staging k offset

    f32x16 acc[2][2] = {};

    for (int k0 = 0; k0 < 512; k0 += 32) {
        // --- stage A: x fp32 -> bf16 ---
        {
            const float4* ap = (const float4*)(x + (size_t)(m0 + srow) * 512 + k0 + sks);
            float4 v0 = ap[0], v1 = ap[1], v2 = ap[2], v3 = ap[3];
            u16x8 a0, a1;
            a0[0] = f2bf(v0.x); a0[1] = f2bf(v0.y); a0[2] = f2bf(v0.z); a0[3] = f2bf(v0.w);
            a0[4] = f2bf(v1.x); a0[5] = f2bf(v1.y); a0[6] = f2bf(v1.z); a0[7] = f2bf(v1.w);
            a1[0] = f2bf(v2.x); a1[1] = f2bf(v2.y); a1[2] = f2bf(v2.z); a1[3] = f2bf(v2.w);
            a1[4] = f2bf(v3.x); a1[5] = f2bf(v3.y); a1[6] = f2bf(v3.z); a1[7] = f2bf(v3.w);
            *(u16x8*)&As[srow * AST + sks]     = a0;
            *(u16x8*)&As[srow * AST + sks + 8] = a1;
        }
        // --- stage B: WT bf16 ---
        {
            const u16x8* bp = (const u16x8*)(WT + (size_t)(n0 + srow) * 512 + k0 + sks);
            *(u16x8*)&Bs[srow * AST + sks]     = bp[0];
            *(u16x8*)&Bs[srow * AST + sks + 8] = bp[1];
        }
        __syncthreads();
#pragma unroll
        for (int ki = 0; ki < 2; ++ki) {
            u16x8 af0 = *(const u16x8*)&As[(mw + lr)      * AST + ki * 16 + lh * 8];
            u16x8 af1 = *(const u16x8*)&As[(mw + 32 + lr) * AST + ki * 16 + lh * 8];
            u16x8 bf0 = *(const u16x8*)&Bs[(nw + lr)      * AST + ki * 16 + lh * 8];
            u16x8 bf1 = *(const u16x8*)&Bs[(nw + 32 + lr) * AST + ki * 16 + lh * 8];
            acc[0][0] = mfma32(af0, bf0, acc[0][0]);
            acc[0][1] = mfma32(af0, bf1, acc[0][1]);
            acc[1][0] = mfma32(af1, bf0, acc[1][0]);
            acc[1][1] = mfma32(af1, bf1, acc[1][1]);
        }
        __syncthreads();
    }

    // --- epilogue: bias + column split (segment is wave-uniform per ni) ---
#pragma unroll
    for (int mi = 0; mi < 2; ++mi) {
#pragma unroll
        for (int ni = 0; ni < 2; ++ni) {
            const int nb = n0 + nw + ni * 32;       // segment base (uniform)
            const int n  = nb + lr;
            const float bv = biasP[n];
            u16* dst; int ld, col;
            if (nb < 64)        { dst = theta; ld = 64;  col = n; }
            else if (nb < 128)  { dst = phiF;  ld = 64;  col = n - 64; }
            else                { dst = gF;    ld = 256; col = n - 128; }
#pragma unroll
            for (int r = 0; r < 16; ++r) {
                int row = m0 + mw + mi * 32 + (r & 3) + 8 * (r >> 2) + 4 * lh;
                dst[(size_t)row * ld + col] = f2bf(acc[mi][ni][r] + bv);
            }
        }
    }
}

// ---------------------------------------------------------------------------
// Kernel 2: 2x2 max-pool of phiF/gF, writing MFMA-FRAGMENT-BLOCKED layouts:
//   phif[b][kb:32][ki:4][slot:64][8]   slot = lr*2+lh; elem j -> phi[kb*32+lr][ki*16+lh*8+j]
//   gtf [b][kb:32][db:8][h:2][slot:64][8]  elem j -> g[kb*32+h*16+lh*8+j][db*32+lr]
// so attn's B-fragment loads are single contiguous 1024-B wave transactions
// (the old [d][k] gt layout made every load a 32-cache-line gather: lane
// stride 2048 B — that gather was the attn kernel's dominant cost).
// ---------------------------------------------------------------------------
__global__ __launch_bounds__(256) void pool_kernel(
    const u16* __restrict__ phiF, const u16* __restrict__ gF,
    u16* __restrict__ phif, u16* __restrict__ gtf)
{
    const int t  = threadIdx.x;
    const int b  = blockIdx.x >> 5;
    const int ph = blockIdx.x & 31;      // = kb

    // --- phi: thread = (pw = t>>3, d-octet = t&7) ---
    {
        const int pw = t >> 3, dq = (t & 7) * 8;
        const u16* base = phiF + ((size_t)(b * NPIX + 2 * ph * 64 + 2 * pw)) * 64 + dq;
        u16x8 v00 = *(const u16x8*)(base);
        u16x8 v01 = *(const u16x8*)(base + 64);
        u16x8 v10 = *(const u16x8*)(base + 64 * 64);
        u16x8 v11 = *(const u16x8*)(base + 64 * 64 + 64);
        u16x8 m;
#pragma unroll
        for (int j = 0; j < 8; ++j) {
            float mf = fmaxf(fmaxf(bf2f(v00[j]), bf2f(v01[j])),
                             fmaxf(bf2f(v10[j]), bf2f(v11[j])));
            m[j] = f2bf(mf);
        }
        const int ki = dq >> 4, lhw = (dq >> 3) & 1;
        *(u16x8*)(phif + (((size_t)(b * 32 + ph) * 4 + ki) * 64 + (pw * 2 + lhw)) * 8) = m;
    }
    // --- g: thread = channel d, loops 32 pool cols; fragment-blocked store ---
    {
        const u16* gb = gF + ((size_t)(b * NPIX + 2 * ph * 64)) * 256 + t;
        u16 buf[32];
#pragma unroll
        for (int kp = 0; kp < 32; ++kp) {
            float m = fmaxf(
                fmaxf(bf2f(gb[(size_t)(2 * kp) * 256]),      bf2f(gb[(size_t)(2 * kp + 1) * 256])),
                fmaxf(bf2f(gb[(size_t)(64 + 2 * kp) * 256]), bf2f(gb[(size_t)(64 + 2 * kp + 1) * 256])));
            buf[kp] = f2bf(m);
        }
        const int db = t >> 5, lr = t & 31;
        u16* go = gtf + (((size_t)(b * 32 + ph) * 8 + db) * 2) * 512;
#pragma unroll
        for (int h = 0; h < 2; ++h)
#pragma unroll
            for (int lhw = 0; lhw < 2; ++lhw)
                *(u16x8*)(go + h * 512 + (lr * 2 + lhw) * 8) =
                    *(const u16x8*)&buf[h * 16 + lhw * 8];
    }
}

// ---------------------------------------------------------------------------
// Kernel 3: MFMA attention — 64 q-rows per block, 512 threads / 8 waves
// (the validated round-2 structure; 132 KB LDS, 1 block/CU).
// Phase 1: wave w computes S cols kb in [w*4, w*4+4) (32-k blocks), both
// q-tiles; phi B-frags come from phif as contiguous coalesced loads.
// Phase 3: wave w owns 32 output cols (db = w), both q-tiles: every gtf
// fragment (contiguous 1024-B load) feeds 4 MFMAs.
// XCD swizzle: 1024 = 8 x 128 (bijective); 2 batches per XCD stay L2-hot.
// ---------------------------------------------------------------------------
#define SLD 1032
__global__ __launch_bounds__(512) void attn_mfma_kernel(
    const u16* __restrict__ theta, const u16* __restrict__ phif,
    const u16* __restrict__ gtf, u16* __restrict__ attn_g)
{
    __shared__ u16   S[64 * SLD];         // 132 KB
    __shared__ float rinv[64];

    const int t  = threadIdx.x;
    const int w  = t >> 6;                // 0..7
    const int l  = t & 63;
    const int lr = l & 31;
    const int lh = l >> 5;
    const int lslot = (lr * 2 + lh) * 8;  // fragment lane slot (u16 units)
    const int sb = (blockIdx.x & 7) * 128 + (blockIdx.x >> 3);   // 1024 = 8*128
    const int b  = sb >> 6;
    const int q0 = (sb & 63) * 64;

    // ---- Phase 1: S = theta @ phi^T  (wave w: kb in [w*4, w*4+4), both q-tiles) ----
    const u16* thb0 = theta + ((size_t)(b * NPIX + q0 + lr)) * CD + lh * 8;
    const u16* thb1 = thb0 + (size_t)32 * CD;
    u16x8 af0[4], af1[4];
#pragma unroll
    for (int ki = 0; ki < 4; ++ki) {
        af0[ki] = *(const u16x8*)(thb0 + ki * 16);
        af1[ki] = *(const u16x8*)(thb1 + ki * 16);
    }

#pragma unroll 2
    for (int nt = 0; nt < 4; ++nt) {
        const int kb = w * 4 + nt;
        const int k0 = kb * 32;
        const u16* pb = phif + ((size_t)(b * 32 + kb) * 4) * 512 + lslot;
        u16x8 pf0 = *(const u16x8*)(pb);
        u16x8 pf1 = *(const u16x8*)(pb + 512);
        u16x8 pf2 = *(const u16x8*)(pb + 1024);
        u16x8 pf3 = *(const u16x8*)(pb + 1536);
        f32x16 acc0 = {}, acc1 = {};
        acc0 = mfma32(af0[0], pf0, acc0);  acc1 = mfma32(af1[0], pf0, acc1);
        acc0 = mfma32(af0[1], pf1, acc0);  acc1 = mfma32(af1[1], pf1, acc1);
        acc0 = mfma32(af0[2], pf2, acc0);  acc1 = mfma32(af1[2], pf2, acc1);
        acc0 = mfma32(af0[3], pf3, acc0);  acc1 = mfma32(af1[3], pf3, acc1);
#pragma unroll
        for (int r = 0; r < 16; ++r) {
            int row = (r & 3) + 8 * (r >> 2) + 4 * lh;
            S[row * SLD + k0 + lr]        = f2bf(acc0[r]);
            S[(32 + row) * SLD + k0 + lr] = f2bf(acc1[r]);
        }
    }
    __syncthreads();

    // ---- Phase 2: rowwise softmax (8 threads per row, 64 rows) ----
    {
        const int row = t >> 3, cg = t & 7;
        u16* srow = S + row * SLD;
        float mx = -1e30f;
#pragma unroll
        for (int i = 0; i < 16; ++i) {
            u16x8 v = *(const u16x8*)(srow + cg * 8 + 64 * i);
#pragma unroll
            for (int j = 0; j < 8; ++j) mx = fmaxf(mx, bf2f(v[j]));
        }
        mx = fmaxf(mx, __shfl_xor(mx, 1));
        mx = fmaxf(mx, __shfl_xor(mx, 2));
        mx = fmaxf(mx, __shfl_xor(mx, 4));
        float sum = 0.f;
#pragma unroll
        for (int i = 0; i < 16; ++i) {
            u16* p = srow + cg * 8 + 64 * i;
            u16x8 v = *(const u16x8*)p;
            u16x8 e;
#pragma unroll
            for (int j = 0; j < 8; ++j) {
                float ev = __expf(bf2f(v[j]) - mx);
                sum += ev;
                e[j] = f2bf(ev);
            }
            *(u16x8*)p = e;
        }
        sum += __shfl_xor(sum, 1);
        sum += __shfl_xor(sum, 2);
        sum += __shfl_xor(sum, 4);
        if (cg == 0) rinv[row] = 1.0f / sum;
    }
    __syncthreads();

    // ---- Phase 3: O = P @ g  (wave w: cols [w*32,w*32+32), both q-tiles) ----
    const u16* gfb = gtf + ((size_t)(b * 32) * 16 + (size_t)w * 2) * 512 + lslot;
    const u16* ar0 = S + lr * SLD;
    const u16* ar1 = S + (32 + lr) * SLD;
    f32x16 o0a = {}, o0b = {}, o1a = {}, o1b = {};
#pragma unroll 4
    for (int kb = 0; kb < 32; ++kb) {
        const u16* gpk = gfb + (size_t)kb * (16 * 512);
        u16x8 b0  = *(const u16x8*)(gpk);          // h=0: k = kb*32 + lh*8+j
        u16x8 b1  = *(const u16x8*)(gpk + 512);    // h=1: k = kb*32 + 16 + lh*8+j
        const int k0 = kb * 32;
        u16x8 a00 = *(const u16x8*)(ar0 + k0 + lh * 8);
        u16x8 a01 = *(const u16x8*)(ar0 + k0 + 16 + lh * 8);
        u16x8 a10 = *(const u16x8*)(ar1 + k0 + lh * 8);
        u16x8 a11 = *(const u16x8*)(ar1 + k0 + 16 + lh * 8);
        o0a = mfma32(a00, b0, o0a);
        o0b = mfma32(a01, b1, o0b);
        o1a = mfma32(a10, b0, o1a);
        o1b = mfma32(a11, b1, o1b);
    }

    u16* obp = attn_g + ((size_t)(b * NPIX + q0)) * CG;
#pragma unroll
    for (int r = 0; r < 16; ++r) {
        int qrow = (r & 3) + 8 * (r >> 2) + 4 * lh;
        float inv0 = rinv[qrow];
        float inv1 = rinv[32 + qrow];
        obp[(size_t)qrow * CG + w * 32 + lr]        = f2bf((o0a[r] + o0b[r]) * inv0);
        obp[(size_t)(32 + qrow) * CG + w * 32 + lr] = f2bf((o1a[r] + o1b[r]) * inv1);
    }
}

// ---------------------------------------------------------------------------
// Kernel 4: out GEMM (MFMA).  out = x + sigma*(attn_g @ wo + bo).
// XCD swizzle: 2048 blocks = 8 x 256.
// ---------------------------------------------------------------------------
__global__ __launch_bounds__(256) void out_gemm_kernel(
    const u16* __restrict__ attn_gB, const u16* __restrict__ WOT,
    const float* __restrict__ x, const float* __restrict__ bo,
    const float* __restrict__ sigma, float* __restrict__ out)
{
    __shared__ u16 As[128 * AST];
    __shared__ u16 Bs[128 * AST];

    const int t  = threadIdx.x;
    const int w  = t >> 6, l = t & 63, lr = l & 31, lh = l >> 5;
    const int sb = (blockIdx.x & 7) * 256 + (blockIdx.x >> 3);   // 2048 = 8*256
    const int mt = sb >> 2, nt = sb & 3;
    const int m0 = mt * 128, n0 = nt * 128;
    const int mw = (w & 1) * 64, nw = (w >> 1) * 64;

    const int srow = t >> 1;
    const int sks  = (t & 1) * 16;

    f32x16 acc[2][2] = {};

    for (int k0 = 0; k0 < 256; k0 += 32) {
        {
            const u16x8* ap = (const u16x8*)(attn_gB + (size_t)(m0 + srow) * 256 + k0 + sks);
            *(u16x8*)&As[srow * AST + sks]     = ap[0];
            *(u16x8*)&As[srow * AST + sks + 8] = ap[1];
        }
        {
            const u16x8* bp = (const u16x8*)(WOT + (size_t)(n0 + srow) * 256 + k0 + sks);
            *(u16x8*)&Bs[srow * AST + sks]     = bp[0];
            *(u16x8*)&Bs[srow * AST + sks + 8] = bp[1];
        }
        __syncthreads();
#pragma unroll
        for (int ki = 0; ki < 2; ++ki) {
            u16x8 af0 = *(const u16x8*)&As[(mw + lr)      * AST + ki * 16 + lh * 8];
            u16x8 af1 = *(const u16x8*)&As[(mw + 32 + lr) * AST + ki * 16 + lh * 8];
            u16x8 bf0 = *(const u16x8*)&Bs[(nw + lr)      * AST + ki * 16 + lh * 8];
            u16x8 bf1 = *(const u16x8*)&Bs[(nw + 32 + lr) * AST + ki * 16 + lh * 8];
            acc[0][0] = mfma32(af0, bf0, acc[0][0]);
            acc[0][1] = mfma32(af0, bf1, acc[0][1]);
            acc[1][0] = mfma32(af1, bf0, acc[1][0]);
            acc[1][1] = mfma32(af1, bf1, acc[1][1]);
        }
        __syncthreads();
    }

    const float s = sigma[0];
#pragma unroll
    for (int mi = 0; mi < 2; ++mi) {
#pragma unroll
        for (int ni = 0; ni < 2; ++ni) {
            const int n  = n0 + nw + ni * 32 + lr;
            const float bv = bo[n];
#pragma unroll
            for (int r = 0; r < 16; ++r) {
                int row = m0 + mw + mi * 32 + (r & 3) + 8 * (r >> 2) + 4 * lh;
                size_t idx = (size_t)row * 512 + n;
                out[idx] = x[idx] + s * (acc[mi][ni][r] + bv);
            }
        }
    }
}

// ---------------------------------------------------------------------------
extern "C" void kernel_launch(void* const* d_in, const int* in_sizes, int n_in,
                              void* d_out, int out_size, void* d_ws, size_t ws_size,
                              hipStream_t stream)
{
    const float* x     = (const float*)d_in[0];
    const float* wt    = (const float*)d_in[1];
    const float* bt    = (const float*)d_in[2];
    const float* wp    = (const float*)d_in[3];
    const float* bp    = (const float*)d_in[4];
    const float* wg    = (const float*)d_in[5];
    const float* bg    = (const float*)d_in[6];
    const float* wo    = (const float*)d_in[7];
    const float* bo    = (const float*)d_in[8];
    const float* sigma = (const float*)d_in[9];
    float* out = (float*)d_out;

    char* ws = (char*)d_ws;
    u16*   theta   = (u16*)(ws);
    u16*   phif    = (u16*)(ws + ((size_t)8  << 20));
    u16*   phiF    = (u16*)(ws + ((size_t)10 << 20));
    u16*   gF      = (u16*)(ws + ((size_t)18 << 20));
    u16*   attn_gB = (u16*)(ws + ((size_t)10 << 20));
    u16*   gtf     = (u16*)(ws + ((size_t)50 << 20));
    u16*   WT      = (u16*)(ws + ((size_t)58 << 20));
    u16*   WOT     = (u16*)(ws + ((size_t)58 << 20) + (384 << 10));
    float* biasP   = (float*)(ws + ((size_t)58 << 20) + (640 << 10));

    prep_kernel<<<321, 256, 0, stream>>>(wt, wp, wg, wo, bt, bp, bg, WT, WOT, biasP);
    proj_gemm_kernel<<<512 * 3, 256, 0, stream>>>(x, WT, biasP, theta, phiF, gF);
    pool_kernel<<<NB * 32, 256, 0, stream>>>(phiF, gF, phif, gtf);
    attn_mfma_kernel<<<NB * NPIX / 64, 512, 0, stream>>>(theta, phif, gtf, attn_gB);
    out_gemm_kernel<<<512 * 4, 256, 0, stream>>>(attn_gB, WOT, x, bo, sigma, out);
}

// Round 6
// 410.899 us; speedup vs baseline: 1.2197x; 1.0160x over previous
//
#include <hip/hip_runtime.h>
#include <math.h>

#define NB    16
#define NPIX  4096    // 64*64
#define NPOOL 1024    // 32*32
#define CIN   512
#define CD    64      // C/8
#define CG    256     // C/2

typedef unsigned short u16;
typedef unsigned int   u32;
typedef __attribute__((ext_vector_type(8)))  u16    u16x8;
typedef __attribute__((ext_vector_type(8)))  __bf16 bf16x8;
typedef __attribute__((ext_vector_type(16))) float  f32x16;

__device__ __forceinline__ u16 f2bf(float x) {
    u32 u = __builtin_bit_cast(u32, x);
    u += 0x7fffu + ((u >> 16) & 1u);          // round-to-nearest-even
    return (u16)(u >> 16);
}
__device__ __forceinline__ float bf2f(u16 h) {
    u32 u = ((u32)h) << 16;
    return __builtin_bit_cast(float, u);
}
__device__ __forceinline__ f32x16 mfma32(u16x8 a, u16x8 b, f32x16 c) {
    return __builtin_amdgcn_mfma_f32_32x32x16_bf16(
        __builtin_bit_cast(bf16x8, a), __builtin_bit_cast(bf16x8, b), c, 0, 0, 0);
}

// ---------------------------------------------------------------------------
// Kernel 0: prep — transpose weights to bf16 [n][k] layout + concat bias.
// ---------------------------------------------------------------------------
__global__ __launch_bounds__(256) void prep_kernel(
    const float* __restrict__ wt, const float* __restrict__ wp,
    const float* __restrict__ wg, const float* __restrict__ wo,
    const float* __restrict__ bt, const float* __restrict__ bp,
    const float* __restrict__ bg,
    u16* __restrict__ WT, u16* __restrict__ WOT, float* __restrict__ biasP)
{
    const int bx = blockIdx.x;
    const int t  = threadIdx.x;

    if (bx == 320) {
        for (int i = t; i < 384; i += 256)
            biasP[i] = (i < 64) ? bt[i] : (i < 128) ? bp[i - 64] : bg[i - 128];
        return;
    }

    const float* src; u16* dst; int N, K, kt, nt;
    if (bx < 32)       { src = wt; dst = WT;             N = 64;  K = 512; kt = bx >> 1;        nt = bx & 1; }
    else if (bx < 64)  { src = wp; dst = WT + 64 * 512;  N = 64;  K = 512; kt = (bx - 32) >> 1; nt = (bx - 32) & 1; }
    else if (bx < 192) { src = wg; dst = WT + 128 * 512; N = 256; K = 512; kt = (bx - 64) >> 3; nt = (bx - 64) & 7; }
    else               { src = wo; dst = WOT;            N = 512; K = 256; kt = (bx - 192) >> 4; nt = (bx - 192) & 15; }

    __shared__ float tile[32][33];
    {
        int r  = t >> 3;            // 0..31 source row (k)
        int c4 = (t & 7) * 4;       // 0..28 source col (n)
        float4 v = *(const float4*)(src + (size_t)(kt * 32 + r) * N + nt * 32 + c4);
        tile[r][c4]     = v.x;
        tile[r][c4 + 1] = v.y;
        tile[r][c4 + 2] = v.z;
        tile[r][c4 + 3] = v.w;
    }
    __syncthreads();
    {
        int n  = t >> 3;            // 0..31 dst row (n)
        int k4 = (t & 7) * 4;       // 0..28 dst col (k)
        ushort4 wv;
        wv.x = f2bf(tile[k4][n]);
        wv.y = f2bf(tile[k4 + 1][n]);
        wv.z = f2bf(tile[k4 + 2][n]);
        wv.w = f2bf(tile[k4 + 3][n]);
        *(ushort4*)(dst + (size_t)(nt * 32 + n) * K + kt * 32 + k4) = wv;
    }
}

// ---------------------------------------------------------------------------
// Kernel 1: proj GEMM (MFMA).  C[65536 x 384] = x(bf16-cast) @ WT^T.
// 128x128 tile, 4 waves each 64x64 (2x2 of 32x32x16 MFMA), BK=32.
// Staging is LINE-DENSE: 8 lanes cover one full 128-B x-row segment per
// instruction (old 2-lane/row map touched 32 lines/inst, 4x amplification
// — the latency*throughput wall this kernel was stuck on).
// XCD swizzle: 1536 = 8 x 192 (bijective).
// ---------------------------------------------------------------------------
#define AST 40   // LDS row stride in bf16 (32 + 8 pad, 80B = 16B-aligned)
__global__ __launch_bounds__(256) void proj_gemm_kernel(
    const float* __restrict__ x, const u16* __restrict__ WT,
    const float* __restrict__ biasP,
    u16* __restrict__ theta, u16* __restrict__ phiF, u16* __restrict__ gF)
{
    __shared__ u16 As[128 * AST];   // 10 KB
    __shared__ u16 Bs[128 * AST];   // 10 KB

    const int t  = threadIdx.x;
    const int w  = t >> 6, l = t & 63, lr = l & 31, lh = l >> 5;
    const int sb = (blockIdx.x & 7) * 192 + (blockIdx.x >> 3);   // 1536 = 8*192
    const int mt = sb / 3, nt = sb % 3;
    const int m0 = mt * 128, n0 = nt * 128;
    const int mw = (w & 1) * 64, nw = (w >> 1) * 64;

    const int arow = t >> 3;            // A: 8 lanes per row (fp32, 128B seg)
    const int ac4  = (t & 7) * 4;       //    16-B chunk within row
    const int brow = t >> 2;            // B: 4 lanes per row (bf16, 64B seg)
    const int bc8  = (t & 3) * 8;       //    16-B chunk within row

    f32x16 acc[2][2] = {};

    for (int k0 = 0; k0 < 512; k0 += 32) {
        // --- stage A: x fp32 -> bf16 (line-dense: 8 lines/inst/wave) ---
#pragma unroll
        for (int i = 0; i < 4; ++i) {
            const int r = i * 32 + arow;
            float4 v = *(const float4*)(x + (size_t)(m0 + r) * 512 + k0 + ac4);
            ushort4 wv;
            wv.x = f2bf(v.x); wv.y = f2bf(v.y); wv.z = f2bf(v.z); wv.w = f2bf(v.w);
            *(ushort4*)&As[r * AST + ac4] = wv;
        }
        // --- stage B: WT bf16 (line-dense: 16 lines/inst/wave) ---
#pragma unroll
        for (int i = 0; i < 2; ++i) {
            const int r = i * 64 + brow;
            u16x8 v = *(const u16x8*)(WT + (size_t)(n0 + r) * 512 + k0 + bc8);
            *(u16x8*)&Bs[r * AST + bc8] = v;
        }
        __syncthreads();
#pragma unroll
        for (int ki = 0; ki < 2; ++ki) {
            u16x8 af0 = *(const u16x8*)&As[(mw + lr)      * AST + ki * 16 + lh * 8];
            u16x8 af1 = *(const u16x8*)&As[(mw + 32 + lr) * AST + ki * 16 + lh * 8];
            u16x8 bf0 = *(const u16x8*)&Bs[(nw + lr)      * AST + ki * 16 + lh * 8];
            u16x8 bf1 = *(const u16x8*)&Bs[(nw + 32 + lr) * AST + ki * 16 + lh * 8];
            acc[0][0] = mfma32(af0, bf0, acc[0][0]);
            acc[0][1] = mfma32(af0, bf1, acc[0][1]);
            acc[1][0] = mfma32(af1, bf0, acc[1][0]);
            acc[1][1] = mfma32(af1, bf1, acc[1][1]);
        }
        __syncthreads();
    }

    // --- epilogue: bias + column split (segment is wave-uniform per ni) ---
#pragma unroll
    for (int mi = 0; mi < 2; ++mi) {
#pragma unroll
        for (int ni = 0; ni < 2; ++ni) {
            const int nb = n0 + nw + ni * 32;       // segment base (uniform)
            const int n  = nb + lr;
            const float bv = biasP[n];
            u16* dst; int ld, col;
            if (nb < 64)        { dst = theta; ld = 64;  col = n; }
            else if (nb < 128)  { dst = phiF;  ld = 64;  col = n - 64; }
            else                { dst = gF;    ld = 256; col = n - 128; }
#pragma unroll
            for (int r = 0; r < 16; ++r) {
                int row = m0 + mw + mi * 32 + (r & 3) + 8 * (r >> 2) + 4 * lh;
                dst[(size_t)row * ld + col] = f2bf(acc[mi][ni][r] + bv);
            }
        }
    }
}

// ---------------------------------------------------------------------------
// Kernel 2: 2x2 max-pool of phiF/gF, writing MFMA-FRAGMENT-BLOCKED layouts:
//   phif[b][kb:32][ki:4][slot:64][8]   slot = lr*2+lh; elem j -> phi[kb*32+lr][ki*16+lh*8+j]
//   gtf [b][kb:32][db:8][h:2][slot:64][8]  elem j -> g[kb*32+h*16+lh*8+j][db*32+lr]
// ---------------------------------------------------------------------------
__global__ __launch_bounds__(256) void pool_kernel(
    const u16* __restrict__ phiF, const u16* __restrict__ gF,
    u16* __restrict__ phif, u16* __restrict__ gtf)
{
    const int t  = threadIdx.x;
    const int b  = blockIdx.x >> 5;
    const int ph = blockIdx.x & 31;      // = kb

    // --- phi: thread = (pw = t>>3, d-octet = t&7) ---
    {
        const int pw = t >> 3, dq = (t & 7) * 8;
        const u16* base = phiF + ((size_t)(b * NPIX + 2 * ph * 64 + 2 * pw)) * 64 + dq;
        u16x8 v00 = *(const u16x8*)(base);
        u16x8 v01 = *(const u16x8*)(base + 64);
        u16x8 v10 = *(const u16x8*)(base + 64 * 64);
        u16x8 v11 = *(const u16x8*)(base + 64 * 64 + 64);
        u16x8 m;
#pragma unroll
        for (int j = 0; j < 8; ++j) {
            float mf = fmaxf(fmaxf(bf2f(v00[j]), bf2f(v01[j])),
                             fmaxf(bf2f(v10[j]), bf2f(v11[j])));
            m[j] = f2bf(mf);
        }
        const int ki = dq >> 4, lhw = (dq >> 3) & 1;
        *(u16x8*)(phif + (((size_t)(b * 32 + ph) * 4 + ki) * 64 + (pw * 2 + lhw)) * 8) = m;
    }
    // --- g: thread = channel d, loops 32 pool cols; fragment-blocked store ---
    {
        const u16* gb = gF + ((size_t)(b * NPIX + 2 * ph * 64)) * 256 + t;
        u16 buf[32];
#pragma unroll
        for (int kp = 0; kp < 32; ++kp) {
            float m = fmaxf(
                fmaxf(bf2f(gb[(size_t)(2 * kp) * 256]),      bf2f(gb[(size_t)(2 * kp + 1) * 256])),
                fmaxf(bf2f(gb[(size_t)(64 + 2 * kp) * 256]), bf2f(gb[(size_t)(64 + 2 * kp + 1) * 256])));
            buf[kp] = f2bf(m);
        }
        const int db = t >> 5, lr = t & 31;
        u16* go = gtf + (((size_t)(b * 32 + ph) * 8 + db) * 2) * 512;
#pragma unroll
        for (int h = 0; h < 2; ++h)
#pragma unroll
            for (int lhw = 0; lhw < 2; ++lhw)
                *(u16x8*)(go + h * 512 + (lr * 2 + lhw) * 8) =
                    *(const u16x8*)&buf[h * 16 + lhw * 8];
    }
}

// ---------------------------------------------------------------------------
// Kernel 3: MFMA attention — 64 q-rows per block, 512 threads / 8 waves
// (validated round-2 structure; 132 KB LDS, 1 block/CU).
// phi/g B-fragments come from fragment-blocked layouts as contiguous
// 1024-B wave loads; each g fragment feeds 4 MFMAs.
// XCD swizzle: 1024 = 8 x 128 (bijective).
// ---------------------------------------------------------------------------
#define SLD 1032
__global__ __launch_bounds__(512) void attn_mfma_kernel(
    const u16* __restrict__ theta, const u16* __restrict__ phif,
    const u16* __restrict__ gtf, u16* __restrict__ attn_g)
{
    __shared__ u16   S[64 * SLD];         // 132 KB
    __shared__ float rinv[64];

    const int t  = threadIdx.x;
    const int w  = t >> 6;                // 0..7
    const int l  = t & 63;
    const int lr = l & 31;
    const int lh = l >> 5;
    const int lslot = (lr * 2 + lh) * 8;  // fragment lane slot (u16 units)
    const int sb = (blockIdx.x & 7) * 128 + (blockIdx.x >> 3);   // 1024 = 8*128
    const int b  = sb >> 6;
    const int q0 = (sb & 63) * 64;

    // ---- Phase 1: S = theta @ phi^T  (wave w: kb in [w*4, w*4+4), both q-tiles) ----
    const u16* thb0 = theta + ((size_t)(b * NPIX + q0 + lr)) * CD + lh * 8;
    const u16* thb1 = thb0 + (size_t)32 * CD;
    u16x8 af0[4], af1[4];
#pragma unroll
    for (int ki = 0; ki < 4; ++ki) {
        af0[ki] = *(const u16x8*)(thb0 + ki * 16);
        af1[ki] = *(const u16x8*)(thb1 + ki * 16);
    }

#pragma unroll 2
    for (int nt = 0; nt < 4; ++nt) {
        const int kb = w * 4 + nt;
        const int k0 = kb * 32;
        const u16* pb = phif + ((size_t)(b * 32 + kb) * 4) * 512 + lslot;
        u16x8 pf0 = *(const u16x8*)(pb);
        u16x8 pf1 = *(const u16x8*)(pb + 512);
        u16x8 pf2 = *(const u16x8*)(pb + 1024);
        u16x8 pf3 = *(const u16x8*)(pb + 1536);
        f32x16 acc0 = {}, acc1 = {};
        acc0 = mfma32(af0[0], pf0, acc0);  acc1 = mfma32(af1[0], pf0, acc1);
        acc0 = mfma32(af0[1], pf1, acc0);  acc1 = mfma32(af1[1], pf1, acc1);
        acc0 = mfma32(af0[2], pf2, acc0);  acc1 = mfma32(af1[2], pf2, acc1);
        acc0 = mfma32(af0[3], pf3, acc0);  acc1 = mfma32(af1[3], pf3, acc1);
#pragma unroll
        for (int r = 0; r < 16; ++r) {
            int row = (r & 3) + 8 * (r >> 2) + 4 * lh;
            S[row * SLD + k0 + lr]        = f2bf(acc0[r]);
            S[(32 + row) * SLD + k0 + lr] = f2bf(acc1[r]);
        }
    }
    __syncthreads();

    // ---- Phase 2: rowwise softmax (8 threads per row, 64 rows) ----
    {
        const int row = t >> 3, cg = t & 7;
        u16* srow = S + row * SLD;
        float mx = -1e30f;
#pragma unroll
        for (int i = 0; i < 16; ++i) {
            u16x8 v = *(const u16x8*)(srow + cg * 8 + 64 * i);
#pragma unroll
            for (int j = 0; j < 8; ++j) mx = fmaxf(mx, bf2f(v[j]));
        }
        mx = fmaxf(mx, __shfl_xor(mx, 1));
        mx = fmaxf(mx, __shfl_xor(mx, 2));
        mx = fmaxf(mx, __shfl_xor(mx, 4));
        float sum = 0.f;
#pragma unroll
        for (int i = 0; i < 16; ++i) {
            u16* p = srow + cg * 8 + 64 * i;
            u16x8 v = *(const u16x8*)p;
            u16x8 e;
#pragma unroll
            for (int j = 0; j < 8; ++j) {
                float ev = __expf(bf2f(v[j]) - mx);
                sum += ev;
                e[j] = f2bf(ev);
            }
            *(u16x8*)p = e;
        }
        sum += __shfl_xor(sum, 1);
        sum += __shfl_xor(sum, 2);
        sum += __shfl_xor(sum, 4);
        if (cg == 0) rinv[row] = 1.0f / sum;
    }
    __syncthreads();

    // ---- Phase 3: O = P @ g  (wave w: cols [w*32,w*32+32), both q-tiles) ----
    const u16* gfb = gtf + ((size_t)(b * 32) * 16 + (size_t)w * 2) * 512 + lslot;
    const u16* ar0 = S + lr * SLD;
    const u16* ar1 = S + (32 + lr) * SLD;
    f32x16 o0a = {}, o0b = {}, o1a = {}, o1b = {};
#pragma unroll 4
    for (int kb = 0; kb < 32; ++kb) {
        const u16* gpk = gfb + (size_t)kb * (16 * 512);
        u16x8 b0  = *(const u16x8*)(gpk);          // h=0: k = kb*32 + lh*8+j
        u16x8 b1  = *(const u16x8*)(gpk + 512);    // h=1: k = kb*32 + 16 + lh*8+j
        const int k0 = kb * 32;
        u16x8 a00 = *(const u16x8*)(ar0 + k0 + lh * 8);
        u16x8 a01 = *(const u16x8*)(ar0 + k0 + 16 + lh * 8);
        u16x8 a10 = *(const u16x8*)(ar1 + k0 + lh * 8);
        u16x8 a11 = *(const u16x8*)(ar1 + k0 + 16 + lh * 8);
        o0a = mfma32(a00, b0, o0a);
        o0b = mfma32(a01, b1, o0b);
        o1a = mfma32(a10, b0, o1a);
        o1b = mfma32(a11, b1, o1b);
    }

    u16* obp = attn_g + ((size_t)(b * NPIX + q0)) * CG;
#pragma unroll
    for (int r = 0; r < 16; ++r) {
        int qrow = (r & 3) + 8 * (r >> 2) + 4 * lh;
        float inv0 = rinv[qrow];
        float inv1 = rinv[32 + qrow];
        obp[(size_t)qrow * CG + w * 32 + lr]        = f2bf((o0a[r] + o0b[r]) * inv0);
        obp[(size_t)(32 + qrow) * CG + w * 32 + lr] = f2bf((o1a[r] + o1b[r]) * inv1);
    }
}

// ---------------------------------------------------------------------------
// Kernel 4: out GEMM (MFMA).  out = x + sigma*(attn_g @ wo + bo).
// Same line-dense staging fix as proj (rows 512 B apart).
// XCD swizzle: 2048 blocks = 8 x 256.
// ---------------------------------------------------------------------------
__global__ __launch_bounds__(256) void out_gemm_kernel(
    const u16* __restrict__ attn_gB, const u16* __restrict__ WOT,
    const float* __restrict__ x, const float* __restrict__ bo,
    const float* __restrict__ sigma, float* __restrict__ out)
{
    __shared__ u16 As[128 * AST];
    __shared__ u16 Bs[128 * AST];

    const int t  = threadIdx.x;
    const int w  = t >> 6, l = t & 63, lr = l & 31, lh = l >> 5;
    const int sb = (blockIdx.x & 7) * 256 + (blockIdx.x >> 3);   // 2048 = 8*256
    const int mt = sb >> 2, nt = sb & 3;
    const int m0 = mt * 128, n0 = nt * 128;
    const int mw = (w & 1) * 64, nw = (w >> 1) * 64;

    const int srow = t >> 2;            // 4 lanes per row (64-B segment)
    const int sc8  = (t & 3) * 8;       // 16-B chunk within row

    f32x16 acc[2][2] = {};

    for (int k0 = 0; k0 < 256; k0 += 32) {
#pragma unroll
        for (int i = 0; i < 2; ++i) {
            const int r = i * 64 + srow;
            u16x8 av = *(const u16x8*)(attn_gB + (size_t)(m0 + r) * 256 + k0 + sc8);
            *(u16x8*)&As[r * AST + sc8] = av;
            u16x8 bv = *(const u16x8*)(WOT + (size_t)(n0 + r) * 256 + k0 + sc8);
            *(u16x8*)&Bs[r * AST + sc8] = bv;
        }
        __syncthreads();
#pragma unroll
        for (int ki = 0; ki < 2; ++ki) {
            u16x8 af0 = *(const u16x8*)&As[(mw + lr)      * AST + ki * 16 + lh * 8];
            u16x8 af1 = *(const u16x8*)&As[(mw + 32 + lr) * AST + ki * 16 + lh * 8];
            u16x8 bf0 = *(const u16x8*)&Bs[(nw + lr)      * AST + ki * 16 + lh * 8];
            u16x8 bf1 = *(const u16x8*)&Bs[(nw + 32 + lr) * AST + ki * 16 + lh * 8];
            acc[0][0] = mfma32(af0, bf0, acc[0][0]);
            acc[0][1] = mfma32(af0, bf1, acc[0][1]);
            acc[1][0] = mfma32(af1, bf0, acc[1][0]);
            acc[1][1] = mfma32(af1, bf1, acc[1][1]);
        }
        __syncthreads();
    }

    const float s = sigma[0];
#pragma unroll
    for (int mi = 0; mi < 2; ++mi) {
#pragma unroll
        for (int ni = 0; ni < 2; ++ni) {
            const int n  = n0 + nw + ni * 32 + lr;
            const float bv = bo[n];
#pragma unroll
            for (int r = 0; r < 16; ++r) {
                int row = m0 + mw + mi * 32 + (r & 3) + 8 * (r >> 2) + 4 * lh;
                size_t idx = (size_t)row * 512 + n;
                out[idx] = x[idx] + s * (acc[mi][ni][r] + bv);
            }
        }
    }
}

// ---------------------------------------------------------------------------
extern "C" void kernel_launch(void* const* d_in, const int* in_sizes, int n_in,
                              void* d_out, int out_size, void* d_ws, size_t ws_size,
                              hipStream_t stream)
{
    const float* x     = (const float*)d_in[0];
    const float* wt    = (const float*)d_in[1];
    const float* bt    = (const float*)d_in[2];
    const float* wp    = (const float*)d_in[3];
    const float* bp    = (const float*)d_in[4];
    const float* wg    = (const float*)d_in[5];
    const float* bg    = (const float*)d_in[6];
    const float* wo    = (const float*)d_in[7];
    const float* bo    = (const float*)d_in[8];
    const float* sigma = (const float*)d_in[9];
    float* out = (float*)d_out;

    char* ws = (char*)d_ws;
    u16*   theta   = (u16*)(ws);
    u16*   phif    = (u16*)(ws + ((size_t)8  << 20));
    u16*   phiF    = (u16*)(ws + ((size_t)10 << 20));
    u16*   gF      = (u16*)(ws + ((size_t)18 << 20));
    u16*   attn_gB = (u16*)(ws + ((size_t)10 << 20));
    u16*   gtf     = (u16*)(ws + ((size_t)50 << 20));
    u16*   WT      = (u16*)(ws + ((size_t)58 << 20));
    u16*   WOT     = (u16*)(ws + ((size_t)58 << 20) + (384 << 10));
    float* biasP   = (float*)(ws + ((size_t)58 << 20) + (640 << 10));

    prep_kernel<<<321, 256, 0, stream>>>(wt, wp, wg, wo, bt, bp, bg, WT, WOT, biasP);
    proj_gemm_kernel<<<512 * 3, 256, 0, stream>>>(x, WT, biasP, theta, phiF, gF);
    pool_kernel<<<NB * 32, 256, 0, stream>>>(phiF, gF, phif, gtf);
    attn_mfma_kernel<<<NB * NPIX / 64, 512, 0, stream>>>(theta, phif, gtf, attn_gB);
    out_gemm_kernel<<<512 * 4, 256, 0, stream>>>(attn_gB, WOT, x, bo, sigma, out);
}